// Round 9
// baseline (256.928 us; speedup 1.0000x reference)
//
#include <hip/hip_runtime.h>
#include <hip/hip_fp16.h>
#include <hip/hip_cooperative_groups.h>
#include <math.h>

namespace cg = cooperative_groups;

#define N_NODES 50000
#define E_EDGES 800000
#define ETOT    (E_EDGES + N_NODES)

// bucket params
#define BUCK_SHIFT 9
#define BUCK_SZ   (1 << BUCK_SHIFT)                               // 512
#define NBUCK ((N_NODES + BUCK_SZ - 1) >> BUCK_SHIFT)             // 98
// cooperative CSR kernel geometry
#define CSR_THREADS 512
#define CSR_EPT 8
#define CSR_EPB (CSR_THREADS * CSR_EPT)                           // 4096
#define CSR_NBLK ((ETOT + CSR_EPB - 1) / CSR_EPB)                 // 208

// ---------------------------------------------------------------------------
// Register-tiled GEMM + alpha epilogue. H written as fp16 (gather payload).
// ---------------------------------------------------------------------------
template<int DIN, int DOUT>
__global__ __launch_bounds__(256)
void gemm_alpha_kernel(const float* __restrict__ X, const float* __restrict__ W,
                       const float* __restrict__ a_s, const float* __restrict__ a_d,
                       __half* __restrict__ H16, float* __restrict__ asrc,
                       float* __restrict__ adst)
{
    constexpr int COLG = DOUT / 4;
    constexpr int ROWG = 256 / COLG;
    constexpr int BM   = ROWG * 4;
    constexpr int K4   = DIN / 4;

    __shared__ float Xl[BM * DIN];
    __shared__ float Wl[DIN * DOUT];

    const int tid = threadIdx.x;
    const int row0b = blockIdx.x * BM;

    constexpr int WV = DIN * DOUT / 4;
    for (int i = tid; i < WV; i += 256)
        ((float4*)Wl)[i] = ((const float4*)W)[i];

    constexpr int XV = BM * K4;
    for (int i = tid; i < XV; i += 256) {
        int r  = i / K4;
        int j  = i % K4;
        int gr = row0b + r;
        float4 v = make_float4(0.f, 0.f, 0.f, 0.f);
        if (gr < N_NODES) v = ((const float4*)X)[gr * K4 + j];
        *(float4*)&Xl[r * DIN + ((j ^ ((r >> 2) & 7)) << 2)] = v;
    }
    __syncthreads();

    const int tx = tid % COLG;
    const int ty = tid / COLG;
    const int r0 = ty * 4;
    const int c0 = tx * 4;
    const int swz = ty & 7;

    float acc[4][4] = {};
    for (int kk = 0; kk < DIN; kk += 4) {
        float a[4][4], w[4][4];
        const int jk = ((kk >> 2) ^ swz) << 2;
#pragma unroll
        for (int i = 0; i < 4; ++i)
            *(float4*)a[i] = *(const float4*)&Xl[(r0 + i) * DIN + jk];
#pragma unroll
        for (int j = 0; j < 4; ++j)
            *(float4*)w[j] = *(const float4*)&Wl[(kk + j) * DOUT + c0];
#pragma unroll
        for (int i = 0; i < 4; ++i)
#pragma unroll
            for (int j = 0; j < 4; ++j)
                acc[i][j] = fmaf(a[i][0], w[0][j],
                            fmaf(a[i][1], w[1][j],
                            fmaf(a[i][2], w[2][j],
                            fmaf(a[i][3], w[3][j], acc[i][j]))));
    }

    float as4[4], ad4[4];
    *(float4*)as4 = *(const float4*)&a_s[c0];
    *(float4*)ad4 = *(const float4*)&a_d[c0];

#pragma unroll
    for (int i = 0; i < 4; ++i) {
        const int gr = row0b + r0 + i;
        float ps = acc[i][0] * as4[0] + acc[i][1] * as4[1] +
                   acc[i][2] * as4[2] + acc[i][3] * as4[3];
        float pd = acc[i][0] * ad4[0] + acc[i][1] * ad4[1] +
                   acc[i][2] * ad4[2] + acc[i][3] * ad4[3];
#pragma unroll
        for (int off = COLG / 2; off >= 1; off >>= 1) {
            ps += __shfl_xor(ps, off, 64);
            pd += __shfl_xor(pd, off, 64);
        }
        if (gr < N_NODES) {
            __half2 p01 = __floats2half2_rn(acc[i][0], acc[i][1]);
            __half2 p23 = __floats2half2_rn(acc[i][2], acc[i][3]);
            uint2 pk;
            pk.x = *(unsigned int*)&p01;
            pk.y = *(unsigned int*)&p23;
            *(uint2*)&H16[gr * DOUT + c0] = pk;
            if (tx == 0) { asrc[gr] = ps; adst[gr] = pd; }
        }
    }
}

// ---------------------------------------------------------------------------
// CSR build — ONE cooperative kernel, 4 phases with grid.sync() between.
//  p1: per-block bucket histogram -> bpart[bucket][block] (no global atomics)
//  p2: block 0 sums + scans -> cur (mutable), cur0 (bases), bcnt
//  p3: binscatter: per-(block,bucket) contiguous runs into tmp
//  p4: blocks 0..97: per-bucket LDS sort -> csr_pk + offs (incl offs[N])
// ---------------------------------------------------------------------------
__global__ __launch_bounds__(CSR_THREADS)
void csr_build_kernel(const int* __restrict__ ei, int* __restrict__ bpart,
                      int* __restrict__ cur, int* __restrict__ cur0,
                      int* __restrict__ bcnt, unsigned int* __restrict__ tmp,
                      unsigned int* __restrict__ csr_pk, int* __restrict__ offs)
{
    cg::grid_group grid = cg::this_grid();
    __shared__ int lcnt[CSR_THREADS];
    __shared__ int lextra[CSR_THREADS];
    const int t   = threadIdx.x;
    const int blk = blockIdx.x;

    // ---- phase 1: per-block bucket histogram
    if (t < NBUCK) lcnt[t] = 0;
    __syncthreads();
    {
        const int e0 = blk * CSR_EPB;
#pragma unroll
        for (int k = 0; k < CSR_EPT; ++k) {
            const int eid = e0 + k * CSR_THREADS + t;
            if (eid < ETOT) {
                int dst = (eid < E_EDGES) ? ei[E_EDGES + eid] : (eid - E_EDGES);
                atomicAdd(&lcnt[dst >> BUCK_SHIFT], 1);
            }
        }
    }
    __syncthreads();
    if (t < NBUCK) bpart[t * CSR_NBLK + blk] = lcnt[t];
    grid.sync();

    // ---- phase 2: block 0 sums partials, scans -> cursors/bases/counts
    if (blk == 0) {
        int v = 0;
        if (t < NBUCK) {
            const int* row = bpart + t * CSR_NBLK;
            for (int i = 0; i < CSR_NBLK; ++i) v += row[i];
        }
        lcnt[t] = (t < NBUCK) ? v : 0;
        __syncthreads();
        for (int off = 1; off < 128; off <<= 1) {
            int u = (t >= off && t < 128) ? lcnt[t - off] : 0;
            __syncthreads();
            if (t < 128) lcnt[t] += u;
            __syncthreads();
        }
        if (t < NBUCK) {
            const int base = lcnt[t] - v;
            cur[t] = base; cur0[t] = base; bcnt[t] = v;
        }
    }
    grid.sync();

    // ---- phase 3: binscatter into bucket-clustered tmp
    {
        if (t < NBUCK) lcnt[t] = 0;
        __syncthreads();
        const int e0 = blk * CSR_EPB;
        unsigned int pk[CSR_EPT];
        int rk[CSR_EPT];
        int bk[CSR_EPT];
#pragma unroll
        for (int k = 0; k < CSR_EPT; ++k) {
            const int eid = e0 + k * CSR_THREADS + t;
            bk[k] = -1;
            if (eid < ETOT) {
                int src, dst;
                if (eid < E_EDGES) { src = ei[eid]; dst = ei[E_EDGES + eid]; }
                else               { src = dst = eid - E_EDGES; }
                bk[k] = dst >> BUCK_SHIFT;
                pk[k] = ((unsigned int)dst << 16) | (unsigned int)src;
                rk[k] = atomicAdd(&lcnt[bk[k]], 1);
            }
        }
        __syncthreads();
        if (t < NBUCK && lcnt[t] > 0) lextra[t] = atomicAdd(&cur[t], lcnt[t]);
        __syncthreads();
#pragma unroll
        for (int k = 0; k < CSR_EPT; ++k)
            if (bk[k] >= 0) tmp[lextra[bk[k]] + rk[k]] = pk[k];
    }
    grid.sync();

    // ---- phase 4: per-bucket LDS sort (blocks 0..NBUCK-1)
    if (blk < NBUCK) {
        const int base = cur0[blk];
        const int cnt  = bcnt[blk];
        lcnt[t] = 0;
        __syncthreads();
        for (int i = t; i < cnt; i += CSR_THREADS)
            atomicAdd(&lcnt[(tmp[base + i] >> 16) & (BUCK_SZ - 1)], 1);
        __syncthreads();
        const int v = lcnt[t];
        lextra[t] = v;
        __syncthreads();
        for (int off = 1; off < BUCK_SZ; off <<= 1) {
            int u = (t >= off) ? lextra[t - off] : 0;
            __syncthreads();
            lextra[t] += u;
            __syncthreads();
        }
        const int excl = lextra[t] - v;
        const int g = (blk << BUCK_SHIFT) + t;
        if (g <= N_NODES) offs[g] = base + excl;   // tail writes offs[N]=ETOT
        lcnt[t] = excl;
        __syncthreads();
        for (int i = t; i < cnt; i += CSR_THREADS) {
            const unsigned int pk = tmp[base + i];
            const int pos = atomicAdd(&lcnt[(pk >> 16) & (BUCK_SZ - 1)], 1);
            csr_pk[base + pos] = pk;
        }
    }
}

// ---------------------------------------------------------------------------
// node_agg v5: inline edge score (FL-redundant, no pbuf pass), 16B fp16
// gathers (8 H-rows in flight for DOUT=64), 1-deep csr_pk prefetch.
// wave = FL feature-lanes (8 feats each) x SLOTS edge-slots.
// ---------------------------------------------------------------------------
template<int DOUT, int ACT>
__global__ __launch_bounds__(256)
void node_agg_kernel(const int* __restrict__ offs,
                     const unsigned int* __restrict__ csr_pk,
                     const float* __restrict__ asrc,
                     const float* __restrict__ adst,
                     const __half* __restrict__ H16,
                     const float* __restrict__ b,
                     float* __restrict__ out)
{
    constexpr int FL    = DOUT / 8;    // 8 (dout=64) or 4 (dout=32)
    constexpr int SLOTS = 64 / FL;     // 8 or 16
    const int wv   = threadIdx.x >> 6;
    const int lane = threadIdx.x & 63;
    const int fl   = lane % FL;
    const int slot = lane / FL;
    const int node = blockIdx.x * 4 + wv;
    if (node >= N_NODES) return;

    const int beg = offs[node];
    const int end = offs[node + 1];
    const float adn = adst[node];
    const __half* __restrict__ Hf = H16 + fl * 8;

    float s = 0.f;
    float acc[8] = {};

    int eid = beg + slot;
    bool valid = (eid < end);
    unsigned int pk = valid ? csr_pk[eid] : 0u;

    for (int cb = beg; cb < end; cb += SLOTS) {
        const int nid = cb + SLOTS + slot;
        const bool nvalid = (nid < end);
        const unsigned int npk = nvalid ? csr_pk[nid] : 0u;

        float p = 0.f;
        uint4 h = make_uint4(0u, 0u, 0u, 0u);
        if (valid) {
            const unsigned int src = pk & 0xffffu;
            float v = asrc[src] + adn;
            v = fmaxf(v, 0.2f * v);              // leaky-relu
            p = __expf(fminf(v, 80.f));
            h = *(const uint4*)(Hf + src * DOUT);
        }
        const float2 f0 = __half22float2(*(const __half2*)&h.x);
        const float2 f1 = __half22float2(*(const __half2*)&h.y);
        const float2 f2 = __half22float2(*(const __half2*)&h.z);
        const float2 f3 = __half22float2(*(const __half2*)&h.w);
        s += p;
        acc[0] = fmaf(p, f0.x, acc[0]);
        acc[1] = fmaf(p, f0.y, acc[1]);
        acc[2] = fmaf(p, f1.x, acc[2]);
        acc[3] = fmaf(p, f1.y, acc[3]);
        acc[4] = fmaf(p, f2.x, acc[4]);
        acc[5] = fmaf(p, f2.y, acc[5]);
        acc[6] = fmaf(p, f3.x, acc[6]);
        acc[7] = fmaf(p, f3.y, acc[7]);
        valid = nvalid;
        pk = npk;
    }

    // reduce partial s/acc across slots
#pragma unroll
    for (int off = FL; off < 64; off <<= 1) {
        s += __shfl_xor(s, off, 64);
#pragma unroll
        for (int j = 0; j < 8; ++j)
            acc[j] += __shfl_xor(acc[j], off, 64);
    }

    if (slot == 0) {
        const float inv = 1.f / s;
        float o[8];
#pragma unroll
        for (int j = 0; j < 8; ++j) {
            float v = acc[j] * inv + b[fl * 8 + j];
            o[j] = (ACT == 0) ? fmaxf(v, 0.f) : tanhf(v);
        }
        *(float4*)&out[node * DOUT + fl * 8]     = *(float4*)&o[0];
        *(float4*)&out[node * DOUT + fl * 8 + 4] = *(float4*)&o[4];
    }
}

// ---------------------------------------------------------------------------

template<int DIN, int DOUT, int ACT>
static void run_layer(const float* X, const float* W, const float* a_s,
                      const float* a_d, const float* b,
                      const int* offs, const unsigned int* csr_pk,
                      __half* H16, float* asrc, float* adst,
                      float* out, hipStream_t stream)
{
    constexpr int COLG = DOUT / 4;
    constexpr int BM = (256 / COLG) * 4;
    const int gemm_grid = (N_NODES + BM - 1) / BM;
    gemm_alpha_kernel<DIN, DOUT><<<gemm_grid, 256, 0, stream>>>(
        X, W, a_s, a_d, H16, asrc, adst);

    const int agg_grid = (N_NODES + 3) / 4;
    node_agg_kernel<DOUT, ACT><<<agg_grid, 256, 0, stream>>>(
        offs, csr_pk, asrc, adst, H16, b, out);
}

extern "C" void kernel_launch(void* const* d_in, const int* in_sizes, int n_in,
                              void* d_out, int out_size, void* d_ws, size_t ws_size,
                              hipStream_t stream)
{
    const float* x  = (const float*)d_in[0];
    const int*   ei = (const int*)d_in[1];
    const float* W0 = (const float*)d_in[2];
    const float* as0= (const float*)d_in[3];
    const float* ad0= (const float*)d_in[4];
    const float* b0 = (const float*)d_in[5];
    const float* W1 = (const float*)d_in[6];
    const float* as1= (const float*)d_in[7];
    const float* ad1= (const float*)d_in[8];
    const float* b1 = (const float*)d_in[9];
    const float* W2 = (const float*)d_in[10];
    const float* as2= (const float*)d_in[11];
    const float* ad2= (const float*)d_in[12];
    const float* b2 = (const float*)d_in[13];
    float* out = (float*)d_out;

    char* wsb = (char*)d_ws;
    auto take = [&](size_t bytes) {
        char* p = wsb;
        wsb += (bytes + 255) & ~size_t(255);
        return p;
    };
    __half* h16    = (__half*)take(sizeof(__half) * N_NODES * 64);
    float* buf_act = (float*)take(sizeof(float) * N_NODES * 64);
    float* asrc    = (float*)take(sizeof(float) * N_NODES);
    float* adst    = (float*)take(sizeof(float) * N_NODES);
    int*   offs    = (int*)take(sizeof(int) * (N_NODES + 1));
    int*   bcnt    = (int*)take(sizeof(int) * NBUCK);
    int*   cur     = (int*)take(sizeof(int) * NBUCK);
    int*   cur0    = (int*)take(sizeof(int) * NBUCK);
    int*   bpart   = (int*)take(sizeof(int) * NBUCK * CSR_NBLK);
    unsigned int* csr_pk = (unsigned int*)take(sizeof(unsigned int) * ETOT);
    // tmp aliases h16: only used inside csr_build, which completes before
    // the first gemm writes h16
    unsigned int* tmp = (unsigned int*)h16;

    {
        void* args[] = { (void*)&ei, (void*)&bpart, (void*)&cur, (void*)&cur0,
                         (void*)&bcnt, (void*)&tmp, (void*)&csr_pk, (void*)&offs };
        hipLaunchCooperativeKernel((const void*)csr_build_kernel,
                                   dim3(CSR_NBLK), dim3(CSR_THREADS),
                                   args, 0, stream);
    }

    run_layer<128, 64, 0>(x, W0, as0, ad0, b0, offs, csr_pk,
                          h16, asrc, adst, buf_act, stream);
    run_layer<64, 64, 0>(buf_act, W1, as1, ad1, b1, offs, csr_pk,
                         h16, asrc, adst, buf_act, stream);
    run_layer<64, 32, 1>(buf_act, W2, as2, ad2, b2, offs, csr_pk,
                         h16, asrc, adst, out, stream);
}

// Round 10
// 184.578 us; speedup vs baseline: 1.3920x; 1.3920x over previous
//
#include <hip/hip_runtime.h>
#include <hip/hip_fp16.h>
#include <math.h>

#define N_NODES 50000
#define E_EDGES 800000
#define ETOT    (E_EDGES + N_NODES)

// bucketed scatter params
#define BUCK_SHIFT 9
#define BUCK_SZ   (1 << BUCK_SHIFT)                               // 512
#define NBUCK ((N_NODES + BUCK_SZ - 1) >> BUCK_SHIFT)             // 98
#define BS_EPT 16
#define BS_THREADS 256
#define BS_EPB (BS_THREADS * BS_EPT)                              // 4096
#define BS_NBLK ((ETOT + BS_EPB - 1) / BS_EPB)

// ---------------------------------------------------------------------------
// Register-tiled GEMM + alpha epilogue. H written as fp16 (gather payload).
// ---------------------------------------------------------------------------
template<int DIN, int DOUT>
__global__ __launch_bounds__(256)
void gemm_alpha_kernel(const float* __restrict__ X, const float* __restrict__ W,
                       const float* __restrict__ a_s, const float* __restrict__ a_d,
                       __half* __restrict__ H16, float* __restrict__ asrc,
                       float* __restrict__ adst)
{
    constexpr int COLG = DOUT / 4;
    constexpr int ROWG = 256 / COLG;
    constexpr int BM   = ROWG * 4;
    constexpr int K4   = DIN / 4;

    __shared__ float Xl[BM * DIN];
    __shared__ float Wl[DIN * DOUT];

    const int tid = threadIdx.x;
    const int row0b = blockIdx.x * BM;

    constexpr int WV = DIN * DOUT / 4;
    for (int i = tid; i < WV; i += 256)
        ((float4*)Wl)[i] = ((const float4*)W)[i];

    constexpr int XV = BM * K4;
    for (int i = tid; i < XV; i += 256) {
        int r  = i / K4;
        int j  = i % K4;
        int gr = row0b + r;
        float4 v = make_float4(0.f, 0.f, 0.f, 0.f);
        if (gr < N_NODES) v = ((const float4*)X)[gr * K4 + j];
        *(float4*)&Xl[r * DIN + ((j ^ ((r >> 2) & 7)) << 2)] = v;
    }
    __syncthreads();

    const int tx = tid % COLG;
    const int ty = tid / COLG;
    const int r0 = ty * 4;
    const int c0 = tx * 4;
    const int swz = ty & 7;

    float acc[4][4] = {};
    for (int kk = 0; kk < DIN; kk += 4) {
        float a[4][4], w[4][4];
        const int jk = ((kk >> 2) ^ swz) << 2;
#pragma unroll
        for (int i = 0; i < 4; ++i)
            *(float4*)a[i] = *(const float4*)&Xl[(r0 + i) * DIN + jk];
#pragma unroll
        for (int j = 0; j < 4; ++j)
            *(float4*)w[j] = *(const float4*)&Wl[(kk + j) * DOUT + c0];
#pragma unroll
        for (int i = 0; i < 4; ++i)
#pragma unroll
            for (int j = 0; j < 4; ++j)
                acc[i][j] = fmaf(a[i][0], w[0][j],
                            fmaf(a[i][1], w[1][j],
                            fmaf(a[i][2], w[2][j],
                            fmaf(a[i][3], w[3][j], acc[i][j]))));
    }

    float as4[4], ad4[4];
    *(float4*)as4 = *(const float4*)&a_s[c0];
    *(float4*)ad4 = *(const float4*)&a_d[c0];

#pragma unroll
    for (int i = 0; i < 4; ++i) {
        const int gr = row0b + r0 + i;
        float ps = acc[i][0] * as4[0] + acc[i][1] * as4[1] +
                   acc[i][2] * as4[2] + acc[i][3] * as4[3];
        float pd = acc[i][0] * ad4[0] + acc[i][1] * ad4[1] +
                   acc[i][2] * ad4[2] + acc[i][3] * ad4[3];
#pragma unroll
        for (int off = COLG / 2; off >= 1; off >>= 1) {
            ps += __shfl_xor(ps, off, 64);
            pd += __shfl_xor(pd, off, 64);
        }
        if (gr < N_NODES) {
            __half2 p01 = __floats2half2_rn(acc[i][0], acc[i][1]);
            __half2 p23 = __floats2half2_rn(acc[i][2], acc[i][3]);
            uint2 pk;
            pk.x = *(unsigned int*)&p01;
            pk.y = *(unsigned int*)&p23;
            *(uint2*)&H16[gr * DOUT + c0] = pk;
            if (tx == 0) { asrc[gr] = ps; adst[gr] = pd; }
        }
    }
}

// ---------------------------------------------------------------------------
// CSR build: zero98 -> hist -> scan98 -> binscatter -> bucket_sort
// (round-8 pipeline: separate kernels overlap ramp/drain; coop version
//  measured 3x slower — phases serialized at worst-phase parallelism)
// ---------------------------------------------------------------------------
__global__ __launch_bounds__(128)
void zero98_kernel(int* __restrict__ bcnt)
{
    int i = threadIdx.x;
    if (i < NBUCK) bcnt[i] = 0;
}

__global__ __launch_bounds__(BS_THREADS)
void hist_kernel(const int* __restrict__ ei, int* __restrict__ bcnt)
{
    __shared__ int lcnt[NBUCK];
    const int t = threadIdx.x;
    for (int i = t; i < NBUCK; i += BS_THREADS) lcnt[i] = 0;
    __syncthreads();
    const int e0 = blockIdx.x * BS_EPB;
#pragma unroll
    for (int k = 0; k < BS_EPT; ++k) {
        const int eid = e0 + k * BS_THREADS + t;
        if (eid < ETOT) {
            int dst = (eid < E_EDGES) ? ei[E_EDGES + eid] : (eid - E_EDGES);
            atomicAdd(&lcnt[dst >> BUCK_SHIFT], 1);
        }
    }
    __syncthreads();
    for (int i = t; i < NBUCK; i += BS_THREADS)
        if (lcnt[i] > 0) atomicAdd(&bcnt[i], lcnt[i]);
}

__global__ __launch_bounds__(128)
void scan98_kernel(const int* __restrict__ bcnt, int* __restrict__ cur,
                   int* __restrict__ cur0)
{
    __shared__ int lds[128];
    const int t = threadIdx.x;
    const int v = (t < NBUCK) ? bcnt[t] : 0;
    lds[t] = v;
    __syncthreads();
    for (int off = 1; off < 128; off <<= 1) {
        int u = (t >= off) ? lds[t - off] : 0;
        __syncthreads();
        lds[t] += u;
        __syncthreads();
    }
    if (t < NBUCK) { cur[t] = lds[t] - v; cur0[t] = lds[t] - v; }
}

__global__ __launch_bounds__(BS_THREADS)
void binscatter_kernel(const int* __restrict__ ei, int* __restrict__ cur,
                       unsigned int* __restrict__ tmp)
{
    __shared__ int lcnt[NBUCK];
    __shared__ int lbase[NBUCK];
    const int t = threadIdx.x;
    for (int i = t; i < NBUCK; i += BS_THREADS) lcnt[i] = 0;
    __syncthreads();

    const int e0 = blockIdx.x * BS_EPB;
    unsigned int pk[BS_EPT];
    int rk[BS_EPT];
    int bk[BS_EPT];
#pragma unroll
    for (int k = 0; k < BS_EPT; ++k) {
        const int eid = e0 + k * BS_THREADS + t;
        bk[k] = -1;
        if (eid < ETOT) {
            int src, dst;
            if (eid < E_EDGES) { src = ei[eid]; dst = ei[E_EDGES + eid]; }
            else               { src = dst = eid - E_EDGES; }
            bk[k] = dst >> BUCK_SHIFT;
            pk[k] = ((unsigned int)dst << 16) | (unsigned int)src;
            rk[k] = atomicAdd(&lcnt[bk[k]], 1);
        }
    }
    __syncthreads();
    for (int i = t; i < NBUCK; i += BS_THREADS)
        if (lcnt[i] > 0) lbase[i] = atomicAdd(&cur[i], lcnt[i]);
    __syncthreads();
#pragma unroll
    for (int k = 0; k < BS_EPT; ++k)
        if (bk[k] >= 0) tmp[lbase[bk[k]] + rk[k]] = pk[k];
}

__global__ __launch_bounds__(BUCK_SZ)
void bucket_sort_kernel(const unsigned int* __restrict__ tmp,
                        const int* __restrict__ cur0,
                        const int* __restrict__ bcnt,
                        unsigned int* __restrict__ csr_pk,
                        int* __restrict__ offs)
{
    __shared__ int lcnt[BUCK_SZ];
    __shared__ int loff[BUCK_SZ];
    __shared__ int lcur[BUCK_SZ];
    const int bk = blockIdx.x;
    const int t  = threadIdx.x;
    const int base = cur0[bk];
    const int cnt  = bcnt[bk];

    lcnt[t] = 0;
    __syncthreads();
    for (int i = t; i < cnt; i += BUCK_SZ)
        atomicAdd(&lcnt[(tmp[base + i] >> 16) & (BUCK_SZ - 1)], 1);
    __syncthreads();

    const int v = lcnt[t];
    loff[t] = v;
    __syncthreads();
    for (int off = 1; off < BUCK_SZ; off <<= 1) {
        int u = (t >= off) ? loff[t - off] : 0;
        __syncthreads();
        loff[t] += u;
        __syncthreads();
    }
    const int excl = loff[t] - v;

    const int g = (bk << BUCK_SHIFT) + t;
    if (g <= N_NODES) offs[g] = base + excl;   // tail node writes offs[N]=ETOT

    lcur[t] = excl;
    __syncthreads();
    for (int i = t; i < cnt; i += BUCK_SZ) {
        const unsigned int pk = tmp[base + i];
        const int l = (pk >> 16) & (BUCK_SZ - 1);
        const int pos = atomicAdd(&lcur[l], 1);
        csr_pk[base + pos] = pk;
    }
}

// ---------------------------------------------------------------------------
// node_agg v5: inline edge score (FL-redundant), 16B fp16 gathers
// (8 H-rows in flight for DOUT=64), 1-deep csr_pk prefetch.
// wave = FL feature-lanes (8 feats each) x SLOTS edge-slots.
// ---------------------------------------------------------------------------
template<int DOUT, int ACT>
__global__ __launch_bounds__(256)
void node_agg_kernel(const int* __restrict__ offs,
                     const unsigned int* __restrict__ csr_pk,
                     const float* __restrict__ asrc,
                     const float* __restrict__ adst,
                     const __half* __restrict__ H16,
                     const float* __restrict__ b,
                     float* __restrict__ out)
{
    constexpr int FL    = DOUT / 8;    // 8 (dout=64) or 4 (dout=32)
    constexpr int SLOTS = 64 / FL;     // 8 or 16
    const int wv   = threadIdx.x >> 6;
    const int lane = threadIdx.x & 63;
    const int fl   = lane % FL;
    const int slot = lane / FL;
    const int node = blockIdx.x * 4 + wv;
    if (node >= N_NODES) return;

    const int beg = offs[node];
    const int end = offs[node + 1];
    const float adn = adst[node];
    const __half* __restrict__ Hf = H16 + fl * 8;

    float s = 0.f;
    float acc[8] = {};

    int eid = beg + slot;
    bool valid = (eid < end);
    unsigned int pk = valid ? csr_pk[eid] : 0u;

    for (int cb = beg; cb < end; cb += SLOTS) {
        const int nid = cb + SLOTS + slot;
        const bool nvalid = (nid < end);
        const unsigned int npk = nvalid ? csr_pk[nid] : 0u;

        float p = 0.f;
        uint4 h = make_uint4(0u, 0u, 0u, 0u);
        if (valid) {
            const unsigned int src = pk & 0xffffu;
            float v = asrc[src] + adn;
            v = fmaxf(v, 0.2f * v);              // leaky-relu
            p = __expf(fminf(v, 80.f));
            h = *(const uint4*)(Hf + src * DOUT);
        }
        const float2 f0 = __half22float2(*(const __half2*)&h.x);
        const float2 f1 = __half22float2(*(const __half2*)&h.y);
        const float2 f2 = __half22float2(*(const __half2*)&h.z);
        const float2 f3 = __half22float2(*(const __half2*)&h.w);
        s += p;
        acc[0] = fmaf(p, f0.x, acc[0]);
        acc[1] = fmaf(p, f0.y, acc[1]);
        acc[2] = fmaf(p, f1.x, acc[2]);
        acc[3] = fmaf(p, f1.y, acc[3]);
        acc[4] = fmaf(p, f2.x, acc[4]);
        acc[5] = fmaf(p, f2.y, acc[5]);
        acc[6] = fmaf(p, f3.x, acc[6]);
        acc[7] = fmaf(p, f3.y, acc[7]);
        valid = nvalid;
        pk = npk;
    }

    // reduce partial s/acc across slots
#pragma unroll
    for (int off = FL; off < 64; off <<= 1) {
        s += __shfl_xor(s, off, 64);
#pragma unroll
        for (int j = 0; j < 8; ++j)
            acc[j] += __shfl_xor(acc[j], off, 64);
    }

    if (slot == 0) {
        const float inv = 1.f / s;
        float o[8];
#pragma unroll
        for (int j = 0; j < 8; ++j) {
            float v = acc[j] * inv + b[fl * 8 + j];
            o[j] = (ACT == 0) ? fmaxf(v, 0.f) : tanhf(v);
        }
        *(float4*)&out[node * DOUT + fl * 8]     = *(float4*)&o[0];
        *(float4*)&out[node * DOUT + fl * 8 + 4] = *(float4*)&o[4];
    }
}

// ---------------------------------------------------------------------------

template<int DIN, int DOUT, int ACT>
static void run_layer(const float* X, const float* W, const float* a_s,
                      const float* a_d, const float* b,
                      const int* offs, const unsigned int* csr_pk,
                      __half* H16, float* asrc, float* adst,
                      float* out, hipStream_t stream)
{
    constexpr int COLG = DOUT / 4;
    constexpr int BM = (256 / COLG) * 4;
    const int gemm_grid = (N_NODES + BM - 1) / BM;
    gemm_alpha_kernel<DIN, DOUT><<<gemm_grid, 256, 0, stream>>>(
        X, W, a_s, a_d, H16, asrc, adst);

    const int agg_grid = (N_NODES + 3) / 4;
    node_agg_kernel<DOUT, ACT><<<agg_grid, 256, 0, stream>>>(
        offs, csr_pk, asrc, adst, H16, b, out);
}

extern "C" void kernel_launch(void* const* d_in, const int* in_sizes, int n_in,
                              void* d_out, int out_size, void* d_ws, size_t ws_size,
                              hipStream_t stream)
{
    const float* x  = (const float*)d_in[0];
    const int*   ei = (const int*)d_in[1];
    const float* W0 = (const float*)d_in[2];
    const float* as0= (const float*)d_in[3];
    const float* ad0= (const float*)d_in[4];
    const float* b0 = (const float*)d_in[5];
    const float* W1 = (const float*)d_in[6];
    const float* as1= (const float*)d_in[7];
    const float* ad1= (const float*)d_in[8];
    const float* b1 = (const float*)d_in[9];
    const float* W2 = (const float*)d_in[10];
    const float* as2= (const float*)d_in[11];
    const float* ad2= (const float*)d_in[12];
    const float* b2 = (const float*)d_in[13];
    float* out = (float*)d_out;

    char* wsb = (char*)d_ws;
    auto take = [&](size_t bytes) {
        char* p = wsb;
        wsb += (bytes + 255) & ~size_t(255);
        return p;
    };
    __half* h16    = (__half*)take(sizeof(__half) * N_NODES * 64);
    float* buf_act = (float*)take(sizeof(float) * N_NODES * 64);
    float* asrc    = (float*)take(sizeof(float) * N_NODES);
    float* adst    = (float*)take(sizeof(float) * N_NODES);
    int*   offs    = (int*)take(sizeof(int) * (N_NODES + 1));
    int*   bcnt    = (int*)take(sizeof(int) * NBUCK);
    int*   cur     = (int*)take(sizeof(int) * NBUCK);
    int*   cur0    = (int*)take(sizeof(int) * NBUCK);
    unsigned int* csr_pk = (unsigned int*)take(sizeof(unsigned int) * ETOT);
    // tmp aliases h16: dead before the first gemm writes H16
    unsigned int* tmp = (unsigned int*)h16;

    zero98_kernel<<<1, 128, 0, stream>>>(bcnt);
    hist_kernel<<<BS_NBLK, BS_THREADS, 0, stream>>>(ei, bcnt);
    scan98_kernel<<<1, 128, 0, stream>>>(bcnt, cur, cur0);
    binscatter_kernel<<<BS_NBLK, BS_THREADS, 0, stream>>>(ei, cur, tmp);
    bucket_sort_kernel<<<NBUCK, BUCK_SZ, 0, stream>>>(tmp, cur0, bcnt,
                                                      csr_pk, offs);

    run_layer<128, 64, 0>(x, W0, as0, ad0, b0, offs, csr_pk,
                          h16, asrc, adst, buf_act, stream);
    run_layer<64, 64, 0>(buf_act, W1, as1, ad1, b1, offs, csr_pk,
                         h16, asrc, adst, buf_act, stream);
    run_layer<64, 32, 1>(buf_act, W2, as2, ad2, b2, offs, csr_pk,
                         h16, asrc, adst, out, stream);
}